// Round 1
// baseline (238.354 us; speedup 1.0000x reference)
//
#include <hip/hip_runtime.h>

// Problem constants (B,D,H,W,K) = (64, 256, 32, 32, 512)
#define DIM   256
#define KCODE 512
#define NPOS  1024        // H*W
#define BATCH 64

#define BPOS 128          // positions per block tile
#define KC   128          // codes per K-chunk
#define DC   32           // D rows staged per chunk
#define TM   8            // per-thread positions
#define TK   8            // per-thread codes

// e_sq[k] = sum_d w[d][k]^2, accumulated in fp64 for accuracy (argmin-flip safety)
__global__ __launch_bounds__(256) void esq_kernel(const float* __restrict__ w,
                                                  float* __restrict__ esq) {
    int k = blockIdx.x * 256 + threadIdx.x;
    if (k >= KCODE) return;
    double s = 0.0;
    for (int d = 0; d < DIM; ++d) {
        double v = (double)w[d * KCODE + k];
        s = fma(v, v, s);
    }
    esq[k] = (float)s;
}

__global__ __launch_bounds__(256, 2) void vq_kernel(const float* __restrict__ x,
                                                    const float* __restrict__ w,
                                                    const float* __restrict__ esq,
                                                    float* __restrict__ quant,
                                                    float* __restrict__ argm) {
    __shared__ float xs[DC][BPOS];     // 16 KiB
    __shared__ float ws[DC][KC];       // 16 KiB
    __shared__ float els[KCODE];       // 2 KiB
    __shared__ float rv[16 * BPOS];    // 8 KiB
    __shared__ int   ri[16 * BPOS];    // 8 KiB
    __shared__ int   idxbuf[BPOS];     // 0.5 KiB

    const int tid  = threadIdx.x;
    const int wave = tid >> 6;          // 0..3
    const int lane = tid & 63;
    const int wm = wave >> 1;           // 0..1  (position half)
    const int wk = wave & 1;            // 0..1  (code half)
    const int lm = lane >> 3;           // 0..7
    const int lk = lane & 7;            // 0..7
    const int mBase = wm * 64 + lm * 8; // position offset in tile (0..120)
    const int kLane = wk * 64 + lk * 8; // code offset in k-chunk (0..120)

    const int p0 = blockIdx.x * BPOS;   // global position base
    const int b  = p0 >> 10;            // / NPOS
    const int n0 = p0 & (NPOS - 1);
    const float* xb = x + (size_t)b * DIM * NPOS + n0;

    // stage e_sq into LDS
    for (int i = tid; i < KCODE; i += 256) els[i] = esq[i];

    float bestVal[TM];
    int   bestIdx[TM];
#pragma unroll
    for (int i = 0; i < TM; ++i) { bestVal[i] = 3.4e38f; bestIdx[i] = 0; }

    for (int kc = 0; kc < KCODE / KC; ++kc) {
        const int k0 = kc * KC;
        float acc[TM][TK];
#pragma unroll
        for (int i = 0; i < TM; ++i)
#pragma unroll
            for (int j = 0; j < TK; ++j) acc[i][j] = 0.f;

        for (int dc = 0; dc < DIM / DC; ++dc) {
            const int d0 = dc * DC;
            __syncthreads();   // protect previous chunk's reads
            // stage xs[32][128] and ws[32][128]: 1024 float4 each, 4 per thread
#pragma unroll
            for (int r = 0; r < 4; ++r) {
                int q   = tid + 256 * r;
                int row = q >> 5;          // 0..31
                int c4  = (q & 31) * 4;    // float offset 0..124
                *(float4*)&xs[row][c4] =
                    *(const float4*)&xb[(size_t)(d0 + row) * NPOS + c4];
                *(float4*)&ws[row][c4] =
                    *(const float4*)&w[(size_t)(d0 + row) * KCODE + k0 + c4];
            }
            __syncthreads();

            float accC[TM][TK];   // per-chunk partial (fp32 error control)
#pragma unroll
            for (int i = 0; i < TM; ++i)
#pragma unroll
                for (int j = 0; j < TK; ++j) accC[i][j] = 0.f;

#pragma unroll 4
            for (int d = 0; d < DC; ++d) {
                const float4 x0 = *(const float4*)&xs[d][mBase];
                const float4 x1 = *(const float4*)&xs[d][mBase + 4];
                const float4 w0 = *(const float4*)&ws[d][kLane];
                const float4 w1 = *(const float4*)&ws[d][kLane + 4];
                const float xm[TM] = {x0.x, x0.y, x0.z, x0.w, x1.x, x1.y, x1.z, x1.w};
                const float wv[TK] = {w0.x, w0.y, w0.z, w0.w, w1.x, w1.y, w1.z, w1.w};
#pragma unroll
                for (int i = 0; i < TM; ++i)
#pragma unroll
                    for (int j = 0; j < TK; ++j)
                        accC[i][j] = fmaf(xm[i], wv[j], accC[i][j]);
            }
#pragma unroll
            for (int i = 0; i < TM; ++i)
#pragma unroll
                for (int j = 0; j < TK; ++j) acc[i][j] += accC[i][j];
        }

        // score = e_sq - 2*cross ; running argmin (first-min tie-break)
#pragma unroll
        for (int j = 0; j < TK; ++j) {
            const int kidx = k0 + kLane + j;
            const float e = els[kidx];
#pragma unroll
            for (int i = 0; i < TM; ++i) {
                const float s = fmaf(-2.f, acc[i][j], e);
                if (s < bestVal[i] || (s == bestVal[i] && kidx < bestIdx[i])) {
                    bestVal[i] = s;
                    bestIdx[i] = kidx;
                }
            }
        }
    }

    // cross-thread reduction: 16 threads (wk,lk) share each position
    const int slot = wk * 8 + lk;   // 0..15
#pragma unroll
    for (int i = 0; i < TM; ++i) {
        rv[slot * BPOS + mBase + i] = bestVal[i];
        ri[slot * BPOS + mBase + i] = bestIdx[i];
    }
    __syncthreads();
    if (tid < BPOS) {
        float bv = rv[tid];
        int   bi = ri[tid];
#pragma unroll
        for (int s = 1; s < 16; ++s) {
            float v  = rv[s * BPOS + tid];
            int   ix = ri[s * BPOS + tid];
            if (v < bv || (v == bv && ix < bi)) { bv = v; bi = ix; }
        }
        idxbuf[tid] = bi;
        argm[(size_t)b * NPOS + n0 + tid] = (float)bi;
    }
    __syncthreads();

    // quant gather-write: coalesced over positions, loop over d
    const int posL = tid & 127;
    const int drow = tid >> 7;      // 0..1
    const int myIdx = idxbuf[posL];
    float* qb = quant + (size_t)b * DIM * NPOS + n0 + posL;
#pragma unroll 4
    for (int dd = 0; dd < DIM / 2; ++dd) {
        const int d = dd * 2 + drow;
        qb[(size_t)d * NPOS] = w[d * KCODE + myIdx];
    }
}

extern "C" void kernel_launch(void* const* d_in, const int* in_sizes, int n_in,
                              void* d_out, int out_size, void* d_ws, size_t ws_size,
                              hipStream_t stream) {
    (void)in_sizes; (void)n_in; (void)out_size; (void)ws_size;
    const float* x = (const float*)d_in[0];
    const float* w = (const float*)d_in[1];
    float* quant = (float*)d_out;
    float* argm  = quant + (size_t)BATCH * DIM * NPOS;
    float* esq   = (float*)d_ws;

    esq_kernel<<<2, 256, 0, stream>>>(w, esq);
    vq_kernel<<<(BATCH * NPOS) / BPOS, 256, 0, stream>>>(x, w, esq, quant, argm);
}

// Round 2
// 145.302 us; speedup vs baseline: 1.6404x; 1.6404x over previous
//
#include <hip/hip_runtime.h>

// (B, D, H, W, K) = (64, 256, 32, 32, 512)
#define DIM    256
#define KCODE  512
#define NPOS   1024
#define BATCH  64
#define NPB    64            // positions per block in main kernel
#define KD     16            // dims per K-step (32x32x16 MFMA)
#define KSTEPS (DIM / KD)    // 16
#define EPS    0.05f         // refine threshold on approx score gap
#define ENT    8             // refine entries per block group

using bf16x8 = __attribute__((ext_vector_type(8))) __bf16;
using f32x16 = __attribute__((ext_vector_type(16))) float;

// workspace layout (bytes)
#define WS_CNT   0
#define WS_ESQ   64
#define WS_WPK   4096
#define WS_LIST  (4096 + 512 * 1024)
// total ~790 KB

// ---------------- prep: e_sq in fp64 + zero refine counter ----------------
__global__ __launch_bounds__(512) void prep_esq(const float* __restrict__ w,
                                                float* __restrict__ esq,
                                                int* __restrict__ cnt) {
    int k = threadIdx.x;
    if (k == 0) *cnt = 0;
    double s = 0.0;
    for (int d = 0; d < DIM; ++d) { double v = (double)w[d * KCODE + k]; s = fma(v, v, s); }
    esq[k] = (float)s;
}

// ---------------- prep: pack w into frag-ready swizzled hi|lo bf16 image ----------------
// layout: for k-step t, code c: 64-byte row = [hi d0..d15 | lo d0..d15], 16B slots
// XOR-swizzled by ((c&3)<<4) so ds_read_b128 of a 32-lane code column is conflict-free.
__global__ __launch_bounds__(256) void prep_wpack(const float* __restrict__ w,
                                                  unsigned char* __restrict__ wpk) {
    int gid = blockIdx.x * 256 + threadIdx.x;   // 16384 = 16t * 2g * 512c
    int c = gid & 511;
    int r = gid >> 9;            // 0..31
    int t = r >> 1, g = r & 1;   // k-step, 8-dim slot
    bf16x8 hi, lo;
#pragma unroll
    for (int j = 0; j < 8; ++j) {
        float v = w[(16 * t + 8 * g + j) * KCODE + c];
        __bf16 h = (__bf16)v;
        hi[j] = h;
        lo[j] = (__bf16)(v - (float)h);
    }
    unsigned char* row = wpk + ((size_t)t * KCODE + c) * 64;
    int sw = (c & 3) << 4;
    *(bf16x8*)(row + ((g * 16) ^ sw))      = hi;
    *(bf16x8*)(row + ((32 + g * 16) ^ sw)) = lo;
}

// ---------------- main: 3-pass split-bf16 MFMA + block-local argmin ----------------
__global__ __launch_bounds__(512, 2) void vq_main(
    const float* __restrict__ x, const unsigned char* __restrict__ wpk,
    const float* __restrict__ esq, const float* __restrict__ w,
    float* __restrict__ quant, float* __restrict__ argm,
    int* __restrict__ cnt, int* __restrict__ list) {

    __shared__ __align__(16) unsigned char At[KCODE * 64];  // 32 KB: 512 codes x 64B
    __shared__ __align__(16) unsigned char Bt[NPB * 64];    //  4 KB: 64 pos x 64B
    __shared__ float esq_s[KCODE];
    __shared__ float red1[8][NPB], red2[8][NPB];
    __shared__ int   redi[8][NPB];
    __shared__ float bestv[NPB];
    __shared__ int   idxbuf[NPB];

    const int tid  = threadIdx.x;
    const int wv   = tid >> 6;       // wave 0..7: codes [wv*64, wv*64+64)
    const int lane = tid & 63;
    const int L    = lane & 31;
    const int h5   = lane >> 5;

    const int p0 = blockIdx.x * NPB;
    const int b  = p0 >> 10;
    const int n0 = p0 & (NPOS - 1);

    for (int i = tid; i < KCODE; i += 512) esq_s[i] = esq[i];

    f32x16 acc[2][2] = {};

    for (int t = 0; t < KSTEPS; ++t) {
        __syncthreads();  // protect previous iteration's LDS reads
        // stage A (codes): 32 KB via global_load_lds, linear dest, pre-swizzled src
        const unsigned char* gA = wpk + (size_t)t * KCODE * 64;
#pragma unroll
        for (int r = 0; r < 4; ++r) {
            __builtin_amdgcn_global_load_lds(
                (const __attribute__((address_space(1))) void*)(gA + r * 8192 + tid * 16),
                (__attribute__((address_space(3))) void*)(At + r * 8192 + tid * 16),
                16, 0, 0);
        }
        // stage B (positions): on-the-fly fp32 -> hi/lo bf16, swizzled ds_write_b128
        if (tid < 128) {
            int pos = tid & 63, g = tid >> 6;
            const float* xp = x + ((size_t)b * DIM + t * KD + g * 8) * NPOS + n0 + pos;
            bf16x8 hi, lo;
#pragma unroll
            for (int j = 0; j < 8; ++j) {
                float v = xp[(size_t)j * NPOS];
                __bf16 h = (__bf16)v;
                hi[j] = h;
                lo[j] = (__bf16)(v - (float)h);
            }
            unsigned char* row = Bt + pos * 64;
            int sw = (pos & 3) << 4;
            *(bf16x8*)(row + ((g * 16) ^ sw))      = hi;
            *(bf16x8*)(row + ((32 + g * 16) ^ sw)) = lo;
        }
        asm volatile("s_waitcnt vmcnt(0)" ::: "memory");
        __syncthreads();

        bf16x8 ah[2], al[2], bh[2], bl[2];
#pragma unroll
        for (int fm = 0; fm < 2; ++fm) {
            int ar = wv * 64 + fm * 32 + L;
            const unsigned char* rp = At + ar * 64;
            int sw = (ar & 3) << 4;
            ah[fm] = *(const bf16x8*)(rp + ((h5 * 16) ^ sw));
            al[fm] = *(const bf16x8*)(rp + ((32 + h5 * 16) ^ sw));
        }
#pragma unroll
        for (int fn = 0; fn < 2; ++fn) {
            int pr = fn * 32 + L;
            const unsigned char* rp = Bt + pr * 64;
            int sw = (pr & 3) << 4;
            bh[fn] = *(const bf16x8*)(rp + ((h5 * 16) ^ sw));
            bl[fn] = *(const bf16x8*)(rp + ((32 + h5 * 16) ^ sw));
        }
#pragma unroll
        for (int fm = 0; fm < 2; ++fm)
#pragma unroll
            for (int fn = 0; fn < 2; ++fn) {
                acc[fm][fn] = __builtin_amdgcn_mfma_f32_32x32x16_bf16(ah[fm], bh[fn], acc[fm][fn], 0, 0, 0);
                acc[fm][fn] = __builtin_amdgcn_mfma_f32_32x32x16_bf16(ah[fm], bl[fn], acc[fm][fn], 0, 0, 0);
                acc[fm][fn] = __builtin_amdgcn_mfma_f32_32x32x16_bf16(al[fm], bh[fn], acc[fm][fn], 0, 0, 0);
            }
    }

    // epilogue: score = e^2 - 2*cross (overwrite acc); per-lane top-2 per position
    float v1[2] = {3.4e38f, 3.4e38f}, v2[2] = {3.4e38f, 3.4e38f};
#pragma unroll
    for (int fm = 0; fm < 2; ++fm)
#pragma unroll
        for (int r = 0; r < 16; ++r) {
            int code = wv * 64 + fm * 32 + (r & 3) + 8 * (r >> 2) + 4 * h5;
            float e = esq_s[code];
#pragma unroll
            for (int fn = 0; fn < 2; ++fn) {
                float s = fmaf(-2.f, acc[fm][fn][r], e);
                acc[fm][fn][r] = s;
                float lo_ = fminf(s, v1[fn]);
                float hi_ = fmaxf(s, v1[fn]);
                v1[fn] = lo_;
                v2[fn] = fminf(v2[fn], hi_);
            }
        }
    // merge lane ^ 32 partner (same position, other half of codes)
#pragma unroll
    for (int fn = 0; fn < 2; ++fn) {
        float o1 = __shfl_xor(v1[fn], 32, 64);
        float o2 = __shfl_xor(v2[fn], 32, 64);
        float mn = fminf(v1[fn], o1);
        float mx = fmaxf(v1[fn], o1);
        v1[fn] = mn;
        v2[fn] = fminf(fminf(v2[fn], o2), mx);
        if (h5 == 0) { red1[wv][fn * 32 + L] = v1[fn]; red2[wv][fn * 32 + L] = v2[fn]; }
    }
    __syncthreads();
    float gapv = 0.f;
    if (tid < NPB) {
        float g1 = red1[0][tid], g2 = red2[0][tid];
#pragma unroll
        for (int wvi = 1; wvi < 8; ++wvi) {
            float a1 = red1[wvi][tid], a2 = red2[wvi][tid];
            float mn = fminf(g1, a1), mx = fmaxf(g1, a1);
            g1 = mn; g2 = fminf(fminf(g2, a2), mx);
        }
        bestv[tid] = g1;
        gapv = g2 - g1;
    }
    __syncthreads();
    // rescan for argmin index (min code among exact matches)
#pragma unroll
    for (int fn = 0; fn < 2; ++fn) {
        float tgt = bestv[fn * 32 + L];
        int cand = 0x7FFFFFFF;
#pragma unroll
        for (int fm = 0; fm < 2; ++fm)
#pragma unroll
            for (int r = 0; r < 16; ++r) {
                int code = wv * 64 + fm * 32 + (r & 3) + 8 * (r >> 2) + 4 * h5;
                if (acc[fm][fn][r] == tgt) cand = min(cand, code);
            }
        int oc = __shfl_xor(cand, 32, 64);
        cand = min(cand, oc);
        if (h5 == 0) redi[wv][fn * 32 + L] = cand;
    }
    __syncthreads();
    if (tid < NPB) {
        int bi = redi[0][tid];
#pragma unroll
        for (int wvi = 1; wvi < 8; ++wvi) bi = min(bi, redi[wvi][tid]);
        idxbuf[tid] = bi;
        argm[(size_t)b * NPOS + n0 + tid] = (float)bi;
        if (gapv < EPS) {            // near-tie: exact refinement will redo this position
            int slot = atomicAdd(cnt, 1);
            list[slot] = p0 + tid;
        }
    }
    __syncthreads();
    // quant gather-write, coalesced over positions
    {
        int pos = tid & 63, dg = tid >> 6;
        int bi = idxbuf[pos];
        float* qb = quant + ((size_t)b * DIM + dg * 32) * NPOS + n0 + pos;
#pragma unroll 4
        for (int dd = 0; dd < 32; ++dd)
            qb[(size_t)dd * NPOS] = w[(dg * 32 + dd) * KCODE + bi];
    }
}

// ---------------- refine: exact fp64 distances for near-tie positions ----------------
__global__ __launch_bounds__(256) void refine(const float* __restrict__ x,
                                              const float* __restrict__ w,
                                              float* __restrict__ quant,
                                              float* __restrict__ argm,
                                              const int* __restrict__ cnt,
                                              const int* __restrict__ list) {
    __shared__ float xs[ENT][DIM];
    __shared__ double dv[256];
    __shared__ int    di[256];
    const int tid = threadIdx.x;
    const int n = *cnt;
    for (int base = blockIdx.x * ENT; base < n; base += gridDim.x * ENT) {
        int nk = min(ENT, n - base);
        for (int e = 0; e < nk; ++e) {
            int p = list[base + e];
            xs[e][tid] = x[((size_t)(p >> 10) * DIM + tid) * NPOS + (p & (NPOS - 1))];
        }
        __syncthreads();
        double a0[ENT], a1[ENT], sw0 = 0.0, sw1 = 0.0;
#pragma unroll
        for (int e = 0; e < ENT; ++e) { a0[e] = 0.0; a1[e] = 0.0; }
        for (int d = 0; d < DIM; ++d) {
            double w0 = (double)w[d * KCODE + tid];
            double w1 = (double)w[d * KCODE + tid + 256];
            sw0 = fma(w0, w0, sw0);
            sw1 = fma(w1, w1, sw1);
#pragma unroll
            for (int e = 0; e < ENT; ++e) {
                double xv = (double)xs[e][d];
                a0[e] = fma(w0, xv, a0[e]);
                a1[e] = fma(w1, xv, a1[e]);
            }
        }
        for (int e = 0; e < nk; ++e) {
            double d0 = sw0 - 2.0 * a0[e];
            double d1 = sw1 - 2.0 * a1[e];
            double bv; int bi;
            if (d1 < d0) { bv = d1; bi = tid + 256; } else { bv = d0; bi = tid; }
            dv[tid] = bv; di[tid] = bi;
            __syncthreads();
            for (int off = 128; off > 0; off >>= 1) {
                if (tid < off) {
                    double ov = dv[tid + off]; int oi = di[tid + off];
                    if (ov < dv[tid] || (ov == dv[tid] && oi < di[tid])) { dv[tid] = ov; di[tid] = oi; }
                }
                __syncthreads();
            }
            int p = list[base + e];
            int bsel = di[0];
            size_t pb = (size_t)(p >> 10), pn = (size_t)(p & (NPOS - 1));
            if (tid == 0) argm[pb * NPOS + pn] = (float)bsel;
            quant[(pb * DIM + tid) * NPOS + pn] = w[tid * KCODE + bsel];
            __syncthreads();
        }
        __syncthreads();
    }
}

extern "C" void kernel_launch(void* const* d_in, const int* in_sizes, int n_in,
                              void* d_out, int out_size, void* d_ws, size_t ws_size,
                              hipStream_t stream) {
    (void)in_sizes; (void)n_in; (void)out_size; (void)ws_size;
    const float* x = (const float*)d_in[0];
    const float* w = (const float*)d_in[1];
    float* quant = (float*)d_out;
    float* argm  = quant + (size_t)BATCH * DIM * NPOS;
    char* ws = (char*)d_ws;
    int*   cnt = (int*)(ws + WS_CNT);
    float* esq = (float*)(ws + WS_ESQ);
    unsigned char* wpk = (unsigned char*)(ws + WS_WPK);
    int*   list = (int*)(ws + WS_LIST);

    prep_esq<<<1, 512, 0, stream>>>(w, esq, cnt);
    prep_wpack<<<64, 256, 0, stream>>>(w, wpk);
    vq_main<<<(BATCH * NPOS) / NPB, 512, 0, stream>>>(x, wpk, esq, w, quant, argm, cnt, list);
    refine<<<256, 256, 0, stream>>>(x, w, quant, argm, cnt, list);
}